// Round 13
// baseline (215.947 us; speedup 1.0000x reference)
//
#include <hip/hip_runtime.h>

constexpr int N_NODES = 100000;
constexpr int E_EDGES = 1600000;
constexpr int IN_C = 128, HID_C = 64, OUT_C = 64;
constexpr int IN_CP = 132;           // padded LDS row (conflict-free 4-row b128 reads)
constexpr int NPAD = 100096;
constexpr int DUMMY = N_NODES;       // all-zero row in g tables
constexpr int BKT_SHIFT = 9;         // 512 nodes per bucket
constexpr int BKT_NODES = 512;
constexpr int NBKT = 196;            // ceil(100000/512)
constexpr int CSR_CAP = 16384;       // ints per bucket csr region
constexpr int CAPB = 16384;          // fixed bbuf slots per bucket (avg ~8192, std ~90)

// ---------------- bf16 helpers (RNE) ----------------
__device__ __forceinline__ unsigned short f2bf(float f) {
    unsigned int u = __float_as_uint(f);
    unsigned int r = (u + 0x7FFFu + ((u >> 16) & 1u)) >> 16;
    return (unsigned short)r;
}
__device__ __forceinline__ float bflo(unsigned int u) {
    return __uint_as_float(u << 16);
}
__device__ __forceinline__ float bfhi(unsigned int u) {
    return __uint_as_float(u & 0xFFFF0000u);
}

// ---------------- P0: zero bucket counters + DUMMY rows ----------------
__global__ void p0_zero(int* __restrict__ bcount,
                        unsigned short* __restrict__ g1, unsigned short* __restrict__ g2) {
    int t = threadIdx.x;
    if (t < NBKT) bcount[t] = 0;
    unsigned int* r1 = (unsigned int*)(g1 + (size_t)N_NODES * 64);
    unsigned int* r2 = (unsigned int*)(g2 + (size_t)N_NODES * 64);
    if (t < 64) { r1[t] = 0u; r2[t] = 0u; }
}

// ---------------- P1: place edges into fixed-capacity coarse buckets ----------------
__global__ __launch_bounds__(256) void p1c_bin(const int* __restrict__ src,
                                               const int* __restrict__ dst,
                                               int* __restrict__ bcount,
                                               unsigned int* __restrict__ bbuf, int E) {
    __shared__ int lc[NBKT], lbase[NBKT];
    for (int i = threadIdx.x; i < NBKT; i += 256) lc[i] = 0;
    __syncthreads();
    int base = blockIdx.x * 4096;
    int s[16], d[16];
    for (int k = 0; k < 16; ++k) {
        int i = base + k * 256 + threadIdx.x;
        s[k] = (i < E) ? src[i] : -1;
        d[k] = (i < E) ? dst[i] : -1;
        if (d[k] >= 0) atomicAdd(&lc[d[k] >> BKT_SHIFT], 1);
    }
    __syncthreads();
    for (int i = threadIdx.x; i < NBKT; i += 256) {
        int c = lc[i];
        lbase[i] = c ? (i * CAPB + atomicAdd(&bcount[i], c)) : 0;
        lc[i] = 0;
    }
    __syncthreads();
    for (int k = 0; k < 16; ++k) {
        if (d[k] >= 0) {
            int b = d[k] >> BKT_SHIFT;
            int pos = lbase[b] + atomicAdd(&lc[b], 1);
            bbuf[pos] = (unsigned)s[k] | ((unsigned)(d[k] & (BKT_NODES - 1)) << 17);
        }
    }
}

// ---------------- P2: per-bucket fine CSR build; SELF-LOOP folded in as first slot ----------------
__global__ __launch_bounds__(256) void p2_build(const unsigned int* __restrict__ bbuf,
                                                const int* __restrict__ bcount,
                                                int* __restrict__ csr,
                                                int* __restrict__ rowbeg,
                                                int* __restrict__ rowend,
                                                float* __restrict__ dinv) {
    __shared__ int cnt[BKT_NODES];
    __shared__ int beg[BKT_NODES];
    __shared__ int cur[BKT_NODES];
    __shared__ int tsum[256];
    int b = blockIdx.x;
    int t = threadIdx.x;
    int e0 = b * CAPB, ec = bcount[b];
    cnt[t] = 0; cnt[t + 256] = 0;
    __syncthreads();
    for (int i = t; i < ec; i += 256) {
        unsigned e = bbuf[e0 + i];
        atomicAdd(&cnt[e >> 17], 1);
    }
    __syncthreads();
    int c0 = cnt[2 * t] + 1;           // +1 self loop
    int c1 = cnt[2 * t + 1] + 1;
    int a0 = (c0 + 7) & ~7;
    int a1 = (c1 + 7) & ~7;
    tsum[t] = a0 + a1;
    __syncthreads();
    for (int off = 1; off < 256; off <<= 1) {
        int v = (t >= off) ? tsum[t - off] : 0;
        __syncthreads();
        tsum[t] += v;
        __syncthreads();
    }
    int excl = tsum[t] - (a0 + a1);
    int gb = b * CSR_CAP;
    beg[2 * t] = excl;
    beg[2 * t + 1] = excl + a0;
    cur[2 * t] = 1; cur[2 * t + 1] = 1;   // slot 0 = self
    int n0 = b * BKT_NODES + 2 * t;
    if (n0 < N_NODES) {
        rowbeg[n0] = gb + excl; rowend[n0] = gb + excl + a0;
        dinv[n0] = rsqrtf((float)c0);      // deg incl self
        csr[gb + excl] = n0;               // self edge
    }
    if (n0 + 1 < N_NODES) {
        rowbeg[n0 + 1] = gb + excl + a0; rowend[n0 + 1] = gb + excl + a0 + a1;
        dinv[n0 + 1] = rsqrtf((float)c1);
        csr[gb + excl + a0] = n0 + 1;
    }
    __syncthreads();
    for (int i = t; i < ec; i += 256) {
        unsigned e = bbuf[e0 + i];
        int ln = e >> 17;
        int pos = beg[ln] + atomicAdd(&cur[ln], 1);
        csr[gb + pos] = (int)(e & 0x1FFFFu);
    }
    __syncthreads();
    {
        int p0 = beg[2 * t] + c0, p0e = beg[2 * t] + a0;
        for (int p = p0; p < p0e; ++p) csr[gb + p] = DUMMY;
        int p1 = beg[2 * t + 1] + c1, p1e = beg[2 * t + 1] + a1;
        for (int p = p1; p < p1e; ++p) csr[gb + p] = DUMMY;
    }
}

// ---------------- paired gather (round-10 proven form): 2 neighbors per wave-load ----------------
__device__ __forceinline__ void gather4(const unsigned short* __restrict__ g,
                                        const int* __restrict__ csr,
                                        int S, int e0, int e1, int e2, int e3, int lane,
                                        float2& A0, float2& A1, float2& A2, float2& A3) {
    const unsigned int* g32 = (const unsigned int*)g;
    int half = lane >> 5;
    int cp = lane & 31;
    float2 a0 = {0.f, 0.f}, a1 = {0.f, 0.f}, a2 = {0.f, 0.f}, a3 = {0.f, 0.f};
    for (int base = S; base < e3; base += 64) {
        int m = min(64, e3 - base);            // multiple of 8
        int sv = (lane < m) ? csr[base + lane] : 0;
        for (int j = 0; j < m; j += 8) {
            int p = base + j;                  // uniform: whole 8-group in one row
            int s0 = __shfl(sv, j + 0 + half);
            int s1 = __shfl(sv, j + 2 + half);
            int s2 = __shfl(sv, j + 4 + half);
            int s3 = __shfl(sv, j + 6 + half);
            unsigned u0 = g32[(size_t)s0 * 32 + cp];
            unsigned u1 = g32[(size_t)s1 * 32 + cp];
            unsigned u2 = g32[(size_t)s2 * 32 + cp];
            unsigned u3 = g32[(size_t)s3 * 32 + cp];
            float tx = (bflo(u0) + bflo(u1)) + (bflo(u2) + bflo(u3));
            float ty = (bfhi(u0) + bfhi(u1)) + (bfhi(u2) + bfhi(u3));
            if (p < e1) {
                if (p < e0) { a0.x += tx; a0.y += ty; } else { a1.x += tx; a1.y += ty; }
            } else {
                if (p < e2) { a2.x += tx; a2.y += ty; } else { a3.x += tx; a3.y += ty; }
            }
        }
    }
    a0.x += __shfl_xor(a0.x, 32); a0.y += __shfl_xor(a0.y, 32);
    a1.x += __shfl_xor(a1.x, 32); a1.y += __shfl_xor(a1.y, 32);
    a2.x += __shfl_xor(a2.x, 32); a2.y += __shfl_xor(a2.y, 32);
    a3.x += __shfl_xor(a3.x, 32); a3.y += __shfl_xor(a3.y, 32);
    A0 = a0; A1 = a1; A2 = a2; A3 = a3;
}

// ---------------- K1: tiled GEMM g1 = bf16((x @ W1) * dinv), 4x4 register blocking ----------------
#define ROWOP(ACC, XR)                                                              \
    ACC[0] += XR.x * w0.x + XR.y * w1.x + XR.z * w2.x + XR.w * w3.x;                \
    ACC[1] += XR.x * w0.y + XR.y * w1.y + XR.z * w2.y + XR.w * w3.y;                \
    ACC[2] += XR.x * w0.z + XR.y * w1.z + XR.z * w2.z + XR.w * w3.z;                \
    ACC[3] += XR.x * w0.w + XR.y * w1.w + XR.z * w2.w + XR.w * w3.w;

__global__ __launch_bounds__(256) void gemm1_kernel(const float* __restrict__ x,
                                                    const float* __restrict__ W1,
                                                    const float* __restrict__ dinv,
                                                    unsigned short* __restrict__ g1) {
    __shared__ float xs[64][IN_CP];
    int n0 = blockIdx.x * 64;
    const float4* xv = (const float4*)(x + (size_t)n0 * IN_C);
    int maxv = (min(64, N_NODES - n0)) * (IN_C / 4);
    for (int i = threadIdx.x; i < 64 * (IN_C / 4); i += 256) {
        float4 v = (i < maxv) ? xv[i] : make_float4(0.f, 0.f, 0.f, 0.f);
        *(float4*)&xs[i >> 5][(i & 31) * 4] = v;
    }
    __syncthreads();
    int cg = (threadIdx.x & 15) * 4;
    int ng = (threadIdx.x >> 4) * 4;
    float acc0[4] = {0.f, 0.f, 0.f, 0.f};
    float acc1[4] = {0.f, 0.f, 0.f, 0.f};
    float acc2[4] = {0.f, 0.f, 0.f, 0.f};
    float acc3[4] = {0.f, 0.f, 0.f, 0.f};
#pragma unroll 4
    for (int k = 0; k < IN_C; k += 4) {
        float4 xr0 = *(const float4*)&xs[ng + 0][k];
        float4 xr1 = *(const float4*)&xs[ng + 1][k];
        float4 xr2 = *(const float4*)&xs[ng + 2][k];
        float4 xr3 = *(const float4*)&xs[ng + 3][k];
        float4 w0 = *(const float4*)&W1[(k + 0) * 64 + cg];
        float4 w1 = *(const float4*)&W1[(k + 1) * 64 + cg];
        float4 w2 = *(const float4*)&W1[(k + 2) * 64 + cg];
        float4 w3 = *(const float4*)&W1[(k + 3) * 64 + cg];
        ROWOP(acc0, xr0)
        ROWOP(acc1, xr1)
        ROWOP(acc2, xr2)
        ROWOP(acc3, xr3)
    }
#pragma unroll
    for (int i = 0; i < 4; ++i) {
        int n = n0 + ng + i;
        if (n < N_NODES) {
            float dv = dinv[n];
            const float* a = (i == 0) ? acc0 : (i == 1) ? acc1 : (i == 2) ? acc2 : acc3;
            ushort4 o;
            o.x = f2bf(a[0] * dv);
            o.y = f2bf(a[1] * dv);
            o.z = f2bf(a[2] * dv);
            o.w = f2bf(a[3] * dv);
            *(ushort4*)&g1[(size_t)n * 64 + cg] = o;
        }
    }
}

// ---------------- K2: 8-row fused gather(g1)+bias+relu -> @W2 -> *dinv -> g2(bf16) ----------------
__global__ __launch_bounds__(256) void fused1_kernel(const unsigned short* __restrict__ g1,
                                                     const int* __restrict__ csr,
                                                     const int* __restrict__ rowbeg,
                                                     const int* __restrict__ rowend,
                                                     const float* __restrict__ dinv,
                                                     const float* __restrict__ b1,
                                                     const float* __restrict__ W2,
                                                     unsigned short* __restrict__ g2) {
    __shared__ float zs[32][64];
    int lane = threadIdx.x & 63;
    int w = threadIdx.x >> 6;
    int cp = lane & 31;
    int d0 = blockIdx.x * 32 + w * 8;
    int S0 = __builtin_amdgcn_readfirstlane(rowbeg[d0]);
    int S1 = __builtin_amdgcn_readfirstlane(rowbeg[d0 + 4]);
    int e0 = __builtin_amdgcn_readfirstlane(rowend[d0 + 0]);
    int e1 = __builtin_amdgcn_readfirstlane(rowend[d0 + 1]);
    int e2 = __builtin_amdgcn_readfirstlane(rowend[d0 + 2]);
    int e3 = __builtin_amdgcn_readfirstlane(rowend[d0 + 3]);
    int e4 = __builtin_amdgcn_readfirstlane(rowend[d0 + 4]);
    int e5 = __builtin_amdgcn_readfirstlane(rowend[d0 + 5]);
    int e6 = __builtin_amdgcn_readfirstlane(rowend[d0 + 6]);
    int e7 = __builtin_amdgcn_readfirstlane(rowend[d0 + 7]);
    float dv0 = dinv[d0 + 0], dv1 = dinv[d0 + 1], dv2 = dinv[d0 + 2], dv3 = dinv[d0 + 3];
    float dv4 = dinv[d0 + 4], dv5 = dinv[d0 + 5], dv6 = dinv[d0 + 6], dv7 = dinv[d0 + 7];
    float2 a0, a1, a2, a3, a4, a5, a6, a7;
    gather4(g1, csr, S0, e0, e1, e2, e3, lane, a0, a1, a2, a3);
    gather4(g1, csr, S1, e4, e5, e6, e7, lane, a4, a5, a6, a7);
    float2 b1v = *(const float2*)&b1[2 * cp];
    int w8 = w * 8;
    if (lane < 32) {
        *(float2*)&zs[w8 + 0][2 * cp] = make_float2(fmaxf(dv0 * a0.x + b1v.x, 0.f), fmaxf(dv0 * a0.y + b1v.y, 0.f));
        *(float2*)&zs[w8 + 1][2 * cp] = make_float2(fmaxf(dv1 * a1.x + b1v.x, 0.f), fmaxf(dv1 * a1.y + b1v.y, 0.f));
        *(float2*)&zs[w8 + 2][2 * cp] = make_float2(fmaxf(dv2 * a2.x + b1v.x, 0.f), fmaxf(dv2 * a2.y + b1v.y, 0.f));
        *(float2*)&zs[w8 + 3][2 * cp] = make_float2(fmaxf(dv3 * a3.x + b1v.x, 0.f), fmaxf(dv3 * a3.y + b1v.y, 0.f));
        *(float2*)&zs[w8 + 4][2 * cp] = make_float2(fmaxf(dv4 * a4.x + b1v.x, 0.f), fmaxf(dv4 * a4.y + b1v.y, 0.f));
        *(float2*)&zs[w8 + 5][2 * cp] = make_float2(fmaxf(dv5 * a5.x + b1v.x, 0.f), fmaxf(dv5 * a5.y + b1v.y, 0.f));
        *(float2*)&zs[w8 + 6][2 * cp] = make_float2(fmaxf(dv6 * a6.x + b1v.x, 0.f), fmaxf(dv6 * a6.y + b1v.y, 0.f));
        *(float2*)&zs[w8 + 7][2 * cp] = make_float2(fmaxf(dv7 * a7.x + b1v.x, 0.f), fmaxf(dv7 * a7.y + b1v.y, 0.f));
    }
    float c_[8];
#pragma unroll
    for (int r = 0; r < 8; ++r) c_[r] = 0.f;
    for (int k4 = 0; k4 < HID_C; k4 += 4) {
        float4 z0 = *(const float4*)&zs[w8 + 0][k4];
        float4 z1 = *(const float4*)&zs[w8 + 1][k4];
        float4 z2 = *(const float4*)&zs[w8 + 2][k4];
        float4 z3 = *(const float4*)&zs[w8 + 3][k4];
        float4 z4 = *(const float4*)&zs[w8 + 4][k4];
        float4 z5 = *(const float4*)&zs[w8 + 5][k4];
        float4 z6 = *(const float4*)&zs[w8 + 6][k4];
        float4 z7 = *(const float4*)&zs[w8 + 7][k4];
#pragma unroll
        for (int kk = 0; kk < 4; ++kk) {
            float wv = W2[(k4 + kk) * 64 + lane];
            c_[0] += ((const float*)&z0)[kk] * wv;
            c_[1] += ((const float*)&z1)[kk] * wv;
            c_[2] += ((const float*)&z2)[kk] * wv;
            c_[3] += ((const float*)&z3)[kk] * wv;
            c_[4] += ((const float*)&z4)[kk] * wv;
            c_[5] += ((const float*)&z5)[kk] * wv;
            c_[6] += ((const float*)&z6)[kk] * wv;
            c_[7] += ((const float*)&z7)[kk] * wv;
        }
    }
    g2[(size_t)(d0 + 0) * 64 + lane] = f2bf(dv0 * c_[0]);
    g2[(size_t)(d0 + 1) * 64 + lane] = f2bf(dv1 * c_[1]);
    g2[(size_t)(d0 + 2) * 64 + lane] = f2bf(dv2 * c_[2]);
    g2[(size_t)(d0 + 3) * 64 + lane] = f2bf(dv3 * c_[3]);
    g2[(size_t)(d0 + 4) * 64 + lane] = f2bf(dv4 * c_[4]);
    g2[(size_t)(d0 + 5) * 64 + lane] = f2bf(dv5 * c_[5]);
    g2[(size_t)(d0 + 6) * 64 + lane] = f2bf(dv6 * c_[6]);
    g2[(size_t)(d0 + 7) * 64 + lane] = f2bf(dv7 * c_[7]);
}

// ---------------- K3: 8-row fused gather(g2)+bias -> decoder @Wd + bd -> out ----------------
__global__ __launch_bounds__(256) void fused2_kernel(const unsigned short* __restrict__ g2,
                                                     const int* __restrict__ csr,
                                                     const int* __restrict__ rowbeg,
                                                     const int* __restrict__ rowend,
                                                     const float* __restrict__ dinv,
                                                     const float* __restrict__ b2,
                                                     const float* __restrict__ Wd,
                                                     const float* __restrict__ bd,
                                                     float* __restrict__ out) {
    __shared__ float zs[32][64];
    int lane = threadIdx.x & 63;
    int w = threadIdx.x >> 6;
    int cp = lane & 31;
    int d0 = blockIdx.x * 32 + w * 8;
    int S0 = __builtin_amdgcn_readfirstlane(rowbeg[d0]);
    int S1 = __builtin_amdgcn_readfirstlane(rowbeg[d0 + 4]);
    int e0 = __builtin_amdgcn_readfirstlane(rowend[d0 + 0]);
    int e1 = __builtin_amdgcn_readfirstlane(rowend[d0 + 1]);
    int e2 = __builtin_amdgcn_readfirstlane(rowend[d0 + 2]);
    int e3 = __builtin_amdgcn_readfirstlane(rowend[d0 + 3]);
    int e4 = __builtin_amdgcn_readfirstlane(rowend[d0 + 4]);
    int e5 = __builtin_amdgcn_readfirstlane(rowend[d0 + 5]);
    int e6 = __builtin_amdgcn_readfirstlane(rowend[d0 + 6]);
    int e7 = __builtin_amdgcn_readfirstlane(rowend[d0 + 7]);
    float dv0 = dinv[d0 + 0], dv1 = dinv[d0 + 1], dv2 = dinv[d0 + 2], dv3 = dinv[d0 + 3];
    float dv4 = dinv[d0 + 4], dv5 = dinv[d0 + 5], dv6 = dinv[d0 + 6], dv7 = dinv[d0 + 7];
    float2 a0, a1, a2, a3, a4, a5, a6, a7;
    gather4(g2, csr, S0, e0, e1, e2, e3, lane, a0, a1, a2, a3);
    gather4(g2, csr, S1, e4, e5, e6, e7, lane, a4, a5, a6, a7);
    float2 b2v = *(const float2*)&b2[2 * cp];
    int w8 = w * 8;
    if (lane < 32) {
        *(float2*)&zs[w8 + 0][2 * cp] = make_float2(dv0 * a0.x + b2v.x, dv0 * a0.y + b2v.y);
        *(float2*)&zs[w8 + 1][2 * cp] = make_float2(dv1 * a1.x + b2v.x, dv1 * a1.y + b2v.y);
        *(float2*)&zs[w8 + 2][2 * cp] = make_float2(dv2 * a2.x + b2v.x, dv2 * a2.y + b2v.y);
        *(float2*)&zs[w8 + 3][2 * cp] = make_float2(dv3 * a3.x + b2v.x, dv3 * a3.y + b2v.y);
        *(float2*)&zs[w8 + 4][2 * cp] = make_float2(dv4 * a4.x + b2v.x, dv4 * a4.y + b2v.y);
        *(float2*)&zs[w8 + 5][2 * cp] = make_float2(dv5 * a5.x + b2v.x, dv5 * a5.y + b2v.y);
        *(float2*)&zs[w8 + 6][2 * cp] = make_float2(dv6 * a6.x + b2v.x, dv6 * a6.y + b2v.y);
        *(float2*)&zs[w8 + 7][2 * cp] = make_float2(dv7 * a7.x + b2v.x, dv7 * a7.y + b2v.y);
    }
    float bdl = bd[lane], bdh = bd[64 + lane];
    float cl_[8], ch_[8];
#pragma unroll
    for (int r = 0; r < 8; ++r) { cl_[r] = bdl; ch_[r] = bdh; }
    for (int k4 = 0; k4 < OUT_C; k4 += 4) {
        float4 z0 = *(const float4*)&zs[w8 + 0][k4];
        float4 z1 = *(const float4*)&zs[w8 + 1][k4];
        float4 z2 = *(const float4*)&zs[w8 + 2][k4];
        float4 z3 = *(const float4*)&zs[w8 + 3][k4];
        float4 z4 = *(const float4*)&zs[w8 + 4][k4];
        float4 z5 = *(const float4*)&zs[w8 + 5][k4];
        float4 z6 = *(const float4*)&zs[w8 + 6][k4];
        float4 z7 = *(const float4*)&zs[w8 + 7][k4];
#pragma unroll
        for (int kk = 0; kk < 4; ++kk) {
            float w0 = Wd[(k4 + kk) * 128 + lane];
            float w1 = Wd[(k4 + kk) * 128 + 64 + lane];
            float zz;
            zz = ((const float*)&z0)[kk]; cl_[0] += zz * w0; ch_[0] += zz * w1;
            zz = ((const float*)&z1)[kk]; cl_[1] += zz * w0; ch_[1] += zz * w1;
            zz = ((const float*)&z2)[kk]; cl_[2] += zz * w0; ch_[2] += zz * w1;
            zz = ((const float*)&z3)[kk]; cl_[3] += zz * w0; ch_[3] += zz * w1;
            zz = ((const float*)&z4)[kk]; cl_[4] += zz * w0; ch_[4] += zz * w1;
            zz = ((const float*)&z5)[kk]; cl_[5] += zz * w0; ch_[5] += zz * w1;
            zz = ((const float*)&z6)[kk]; cl_[6] += zz * w0; ch_[6] += zz * w1;
            zz = ((const float*)&z7)[kk]; cl_[7] += zz * w0; ch_[7] += zz * w1;
        }
    }
#pragma unroll
    for (int r = 0; r < 8; ++r) {
        out[(size_t)(d0 + r) * 128 + lane] = cl_[r];
        out[(size_t)(d0 + r) * 128 + 64 + lane] = ch_[r];
    }
}

extern "C" void kernel_launch(void* const* d_in, const int* in_sizes, int n_in,
                              void* d_out, int out_size, void* d_ws, size_t ws_size,
                              hipStream_t stream) {
    const float* x = (const float*)d_in[0];
    const int* ei = (const int*)d_in[1];  // int64 ref -> int32 from harness
    const int* src = ei;
    const int* dst = ei + E_EDGES;
    const float* W1 = (const float*)d_in[2];
    const float* b1 = (const float*)d_in[3];
    const float* W2 = (const float*)d_in[4];
    const float* b2 = (const float*)d_in[5];
    const float* Wd = (const float*)d_in[6];
    const float* bd = (const float*)d_in[7];
    float* out = (float*)d_out;

    // ws layout (4-byte units):
    // bcount[256] | rowbeg[NPAD] | rowend[NPAD] | dinv[NPAD] | csr[NBKT*CSR_CAP] | g2[(N+1)*64 bf16]
    int* bcount = (int*)d_ws;
    int* rowbeg = bcount + 256;
    int* rowend = rowbeg + NPAD;
    float* dinv = (float*)(rowend + NPAD);
    int* csr = (int*)(dinv + NPAD);
    unsigned short* g2 = (unsigned short*)(csr + NBKT * CSR_CAP);
    // aliases into d_out (51.2 MB): g1 at [0, 12.82MB), bbuf at [16MB, 28.9MB)
    unsigned short* g1 = (unsigned short*)out;            // dead before fused2 writes out
    unsigned int* bbuf = (unsigned int*)((char*)d_out + 16000000);  // dead after p2_build

    const int B = 256;
    const int EB = (E_EDGES + 4095) / 4096;  // 391

    // ---- build bucketed CSR (self-loops folded in) + rowbeg/rowend/dinv ----
    p0_zero<<<1, B, 0, stream>>>(bcount, g1, g2);
    p1c_bin<<<EB, B, 0, stream>>>(src, dst, bcount, bbuf, E_EDGES);
    p2_build<<<NBKT, B, 0, stream>>>(bbuf, bcount, csr, rowbeg, rowend, dinv);

    // ---- layer 1 transform: g1 = bf16((x @ W1) * dinv) ----
    gemm1_kernel<<<(N_NODES + 63) / 64, B, 0, stream>>>(x, W1, dinv, g1);
    // ---- fused: aggregate(g1) + b1 + relu, @W2, *dinv -> g2 ----
    fused1_kernel<<<N_NODES / 32, B, 0, stream>>>(g1, csr, rowbeg, rowend, dinv, b1, W2, g2);
    // ---- fused: aggregate(g2) + b2, decoder @Wd + bd -> out ----
    fused2_kernel<<<N_NODES / 32, B, 0, stream>>>(g2, csr, rowbeg, rowend, dinv, b2, Wd, bd, out);
}

// Round 14
// 173.190 us; speedup vs baseline: 1.2469x; 1.2469x over previous
//
#include <hip/hip_runtime.h>

constexpr int N_NODES = 100000;
constexpr int E_EDGES = 1600000;
constexpr int IN_C = 128, HID_C = 64, OUT_C = 64;
constexpr int NPAD = 100096;
constexpr int DUMMY = N_NODES;       // all-zero row in g tables
constexpr int BKT_SHIFT = 9;         // 512 nodes per bucket
constexpr int BKT_NODES = 512;
constexpr int NBKT = 196;            // ceil(100000/512)
constexpr int CSR_CAP = 16384;       // ints per bucket csr region
constexpr int CAPB = 16384;          // fixed bbuf slots per bucket (avg ~8192, std ~90)

typedef __attribute__((ext_vector_type(8))) short bf16x8;
typedef __attribute__((ext_vector_type(4))) float f32x4;

// ---------------- bf16 helpers (RNE) ----------------
__device__ __forceinline__ unsigned short f2bf(float f) {
    unsigned int u = __float_as_uint(f);
    unsigned int r = (u + 0x7FFFu + ((u >> 16) & 1u)) >> 16;
    return (unsigned short)r;
}
__device__ __forceinline__ float bflo(unsigned int u) {
    return __uint_as_float(u << 16);
}
__device__ __forceinline__ float bfhi(unsigned int u) {
    return __uint_as_float(u & 0xFFFF0000u);
}

// ---------------- P0: zero bucket counters + DUMMY rows ----------------
__global__ void p0_zero(int* __restrict__ bcount,
                        unsigned short* __restrict__ g1, unsigned short* __restrict__ g2) {
    int t = threadIdx.x;
    if (t < NBKT) bcount[t] = 0;
    unsigned int* r1 = (unsigned int*)(g1 + (size_t)N_NODES * 64);
    unsigned int* r2 = (unsigned int*)(g2 + (size_t)N_NODES * 64);
    if (t < 64) { r1[t] = 0u; r2[t] = 0u; }
}

// ---------------- P1: place edges into fixed-capacity coarse buckets ----------------
__global__ __launch_bounds__(256) void p1c_bin(const int* __restrict__ src,
                                               const int* __restrict__ dst,
                                               int* __restrict__ bcount,
                                               unsigned int* __restrict__ bbuf, int E) {
    __shared__ int lc[NBKT], lbase[NBKT];
    for (int i = threadIdx.x; i < NBKT; i += 256) lc[i] = 0;
    __syncthreads();
    int base = blockIdx.x * 4096;
    int s[16], d[16];
    for (int k = 0; k < 16; ++k) {
        int i = base + k * 256 + threadIdx.x;
        s[k] = (i < E) ? src[i] : -1;
        d[k] = (i < E) ? dst[i] : -1;
        if (d[k] >= 0) atomicAdd(&lc[d[k] >> BKT_SHIFT], 1);
    }
    __syncthreads();
    for (int i = threadIdx.x; i < NBKT; i += 256) {
        int c = lc[i];
        lbase[i] = c ? (i * CAPB + atomicAdd(&bcount[i], c)) : 0;
        lc[i] = 0;
    }
    __syncthreads();
    for (int k = 0; k < 16; ++k) {
        if (d[k] >= 0) {
            int b = d[k] >> BKT_SHIFT;
            int pos = lbase[b] + atomicAdd(&lc[b], 1);
            bbuf[pos] = (unsigned)s[k] | ((unsigned)(d[k] & (BKT_NODES - 1)) << 17);
        }
    }
}

// ---------------- P2: per-bucket fine CSR build + rowbeg/rowend/dinv + pad ----------------
__global__ __launch_bounds__(256) void p2_build(const unsigned int* __restrict__ bbuf,
                                                const int* __restrict__ bcount,
                                                int* __restrict__ csr,
                                                int* __restrict__ rowbeg,
                                                int* __restrict__ rowend,
                                                float* __restrict__ dinv) {
    __shared__ int cnt[BKT_NODES];
    __shared__ int beg[BKT_NODES];
    __shared__ int cur[BKT_NODES];
    __shared__ int tsum[256];
    int b = blockIdx.x;
    int t = threadIdx.x;
    int e0 = b * CAPB, ec = bcount[b];
    cnt[t] = 0; cnt[t + 256] = 0;
    __syncthreads();
    for (int i = t; i < ec; i += 256) {
        unsigned e = bbuf[e0 + i];
        atomicAdd(&cnt[e >> 17], 1);
    }
    __syncthreads();
    int c0 = cnt[2 * t], c1 = cnt[2 * t + 1];
    int a0 = (c0 + 7) & ~7;
    int a1 = (c1 + 7) & ~7;
    tsum[t] = a0 + a1;
    __syncthreads();
    for (int off = 1; off < 256; off <<= 1) {
        int v = (t >= off) ? tsum[t - off] : 0;
        __syncthreads();
        tsum[t] += v;
        __syncthreads();
    }
    int excl = tsum[t] - (a0 + a1);
    int gb = b * CSR_CAP;
    beg[2 * t] = excl;
    beg[2 * t + 1] = excl + a0;
    cur[2 * t] = 0; cur[2 * t + 1] = 0;
    int n0 = b * BKT_NODES + 2 * t;
    if (n0 < N_NODES) {
        rowbeg[n0] = gb + excl; rowend[n0] = gb + excl + a0;
        dinv[n0] = rsqrtf((float)c0 + 1.0f);
    }
    if (n0 + 1 < N_NODES) {
        rowbeg[n0 + 1] = gb + excl + a0; rowend[n0 + 1] = gb + excl + a0 + a1;
        dinv[n0 + 1] = rsqrtf((float)c1 + 1.0f);
    }
    __syncthreads();
    for (int i = t; i < ec; i += 256) {
        unsigned e = bbuf[e0 + i];
        int ln = e >> 17;
        int pos = beg[ln] + atomicAdd(&cur[ln], 1);
        csr[gb + pos] = (int)(e & 0x1FFFFu);
    }
    __syncthreads();
    {
        int p0 = beg[2 * t] + c0, p0e = beg[2 * t] + a0;
        for (int p = p0; p < p0e; ++p) csr[gb + p] = DUMMY;
        int p1 = beg[2 * t + 1] + c1, p1e = beg[2 * t + 1] + a1;
        for (int p = p1; p < p1e; ++p) csr[gb + p] = DUMMY;
    }
}

// ---------------- paired gather (R10 proven form): 2 neighbors per wave-load ----------------
__device__ __forceinline__ void gather4(const unsigned short* __restrict__ g,
                                        const int* __restrict__ csr,
                                        int S, int e0, int e1, int e2, int e3, int lane,
                                        float2& A0, float2& A1, float2& A2, float2& A3) {
    const unsigned int* g32 = (const unsigned int*)g;
    int half = lane >> 5;
    int cp = lane & 31;
    float2 a0 = {0.f, 0.f}, a1 = {0.f, 0.f}, a2 = {0.f, 0.f}, a3 = {0.f, 0.f};
    for (int base = S; base < e3; base += 64) {
        int m = min(64, e3 - base);            // multiple of 8
        int sv = (lane < m) ? csr[base + lane] : 0;
        for (int j = 0; j < m; j += 8) {
            int p = base + j;                  // uniform: whole 8-group in one row
            int s0 = __shfl(sv, j + 0 + half);
            int s1 = __shfl(sv, j + 2 + half);
            int s2 = __shfl(sv, j + 4 + half);
            int s3 = __shfl(sv, j + 6 + half);
            unsigned u0 = g32[(size_t)s0 * 32 + cp];
            unsigned u1 = g32[(size_t)s1 * 32 + cp];
            unsigned u2 = g32[(size_t)s2 * 32 + cp];
            unsigned u3 = g32[(size_t)s3 * 32 + cp];
            float tx = (bflo(u0) + bflo(u1)) + (bflo(u2) + bflo(u3));
            float ty = (bfhi(u0) + bfhi(u1)) + (bfhi(u2) + bfhi(u3));
            if (p < e1) {
                if (p < e0) { a0.x += tx; a0.y += ty; } else { a1.x += tx; a1.y += ty; }
            } else {
                if (p < e2) { a2.x += tx; a2.y += ty; } else { a3.x += tx; a3.y += ty; }
            }
        }
    }
    a0.x += __shfl_xor(a0.x, 32); a0.y += __shfl_xor(a0.y, 32);
    a1.x += __shfl_xor(a1.x, 32); a1.y += __shfl_xor(a1.y, 32);
    a2.x += __shfl_xor(a2.x, 32); a2.y += __shfl_xor(a2.y, 32);
    a3.x += __shfl_xor(a3.x, 32); a3.y += __shfl_xor(a3.y, 32);
    A0 = a0; A1 = a1; A2 = a2; A3 = a3;
}

// ---------------- K1: MFMA GEMM g1 = bf16((x @ W1) * dinv) ----------------
// Block = 64 nodes x 64 cols, K=128. x and W1^T staged as bf16 in LDS (pad 136).
// Wave w computes nodes [16w,16w+16) x all 64 cols via 16 mfma_f32_16x16x32_bf16.
__global__ __launch_bounds__(256) void gemm1_kernel(const float* __restrict__ x,
                                                    const float* __restrict__ W1,
                                                    const float* __restrict__ dinv,
                                                    unsigned short* __restrict__ g1) {
    __shared__ unsigned short xsb[64 * 136];   // x tile, bf16, row stride 136 (272B, 16B-aligned)
    __shared__ unsigned short wt[64 * 136];    // W1^T: wt[c*136 + k], bf16
    int t = threadIdx.x;
    int n0 = blockIdx.x * 64;
    // stage x tile (64x128 fp32 -> bf16), coalesced float4 reads
    const float4* xv = (const float4*)(x + (size_t)n0 * IN_C);
    int maxv = min(64, N_NODES - n0) * 32;
    for (int i = t; i < 2048; i += 256) {
        float4 v = (i < maxv) ? xv[i] : make_float4(0.f, 0.f, 0.f, 0.f);
        int r = i >> 5, c4 = (i & 31) * 4;
        ushort4 o;
        o.x = f2bf(v.x); o.y = f2bf(v.y); o.z = f2bf(v.z); o.w = f2bf(v.w);
        *(ushort4*)&xsb[r * 136 + c4] = o;
    }
    // stage W1 transposed: thread -> col c = t&63, k-chunk (t>>6)*32
    {
        int c = t & 63, k0 = (t >> 6) * 32;
        for (int kk = 0; kk < 32; ++kk)
            wt[c * 136 + k0 + kk] = f2bf(W1[(k0 + kk) * 64 + c]);
    }
    __syncthreads();
    int w = t >> 6, lane = t & 63;
    int fr = lane & 15;          // fragment free-dim index
    int ak = (lane >> 4) * 8;    // 8 consecutive k per lane-group
    int arow = w * 16 + fr;
    bf16x8 afrag[4];
#pragma unroll
    for (int kc = 0; kc < 4; ++kc)
        afrag[kc] = *(const bf16x8*)&xsb[arow * 136 + kc * 32 + ak];
    f32x4 acc[4];
#pragma unroll
    for (int ni = 0; ni < 4; ++ni) acc[ni] = (f32x4){0.f, 0.f, 0.f, 0.f};
#pragma unroll
    for (int ni = 0; ni < 4; ++ni) {
#pragma unroll
        for (int kc = 0; kc < 4; ++kc) {
            bf16x8 bfrag = *(const bf16x8*)&wt[(ni * 16 + fr) * 136 + kc * 32 + ak];
            acc[ni] = __builtin_amdgcn_mfma_f32_16x16x32_bf16(afrag[kc], bfrag, acc[ni], 0, 0, 0);
        }
    }
    // C/D layout: col = lane&15, row = (lane>>4)*4 + reg
#pragma unroll
    for (int j = 0; j < 4; ++j) {
        int node = n0 + w * 16 + (lane >> 4) * 4 + j;
        if (node < N_NODES) {
            float dv = dinv[node];
#pragma unroll
            for (int ni = 0; ni < 4; ++ni)
                g1[(size_t)node * 64 + ni * 16 + fr] = f2bf(acc[ni][j] * dv);
        }
    }
}

// ---------------- K2: 4-row fused gather(g1)+bias+relu -> @W2 -> *dinv -> g2(bf16) ----------------
__global__ __launch_bounds__(256) void fused1_kernel(const unsigned short* __restrict__ g1,
                                                     const int* __restrict__ csr,
                                                     const int* __restrict__ rowbeg,
                                                     const int* __restrict__ rowend,
                                                     const float* __restrict__ dinv,
                                                     const float* __restrict__ b1,
                                                     const float* __restrict__ W2,
                                                     unsigned short* __restrict__ g2) {
    __shared__ float zs[16][64];
    int lane = threadIdx.x & 63;
    int w = threadIdx.x >> 6;
    int cp = lane & 31;
    int d0 = blockIdx.x * 16 + w * 4;
    int S  = __builtin_amdgcn_readfirstlane(rowbeg[d0]);
    int e0 = __builtin_amdgcn_readfirstlane(rowend[d0 + 0]);
    int e1 = __builtin_amdgcn_readfirstlane(rowend[d0 + 1]);
    int e2 = __builtin_amdgcn_readfirstlane(rowend[d0 + 2]);
    int e3 = __builtin_amdgcn_readfirstlane(rowend[d0 + 3]);
    float dv0 = dinv[d0 + 0], dv1 = dinv[d0 + 1], dv2 = dinv[d0 + 2], dv3 = dinv[d0 + 3];
    float2 a0, a1, a2, a3;
    gather4(g1, csr, S, e0, e1, e2, e3, lane, a0, a1, a2, a3);
    const unsigned int* g32 = (const unsigned int*)g1;
    unsigned su0 = g32[(size_t)(d0 + 0) * 32 + cp];
    unsigned su1 = g32[(size_t)(d0 + 1) * 32 + cp];
    unsigned su2 = g32[(size_t)(d0 + 2) * 32 + cp];
    unsigned su3 = g32[(size_t)(d0 + 3) * 32 + cp];
    float2 b1v = *(const float2*)&b1[2 * cp];
    int w4 = w * 4;
    if (lane < 32) {
        float2 z0 = make_float2(fmaxf(dv0 * (a0.x + bflo(su0)) + b1v.x, 0.f),
                                fmaxf(dv0 * (a0.y + bfhi(su0)) + b1v.y, 0.f));
        float2 z1 = make_float2(fmaxf(dv1 * (a1.x + bflo(su1)) + b1v.x, 0.f),
                                fmaxf(dv1 * (a1.y + bfhi(su1)) + b1v.y, 0.f));
        float2 z2 = make_float2(fmaxf(dv2 * (a2.x + bflo(su2)) + b1v.x, 0.f),
                                fmaxf(dv2 * (a2.y + bfhi(su2)) + b1v.y, 0.f));
        float2 z3 = make_float2(fmaxf(dv3 * (a3.x + bflo(su3)) + b1v.x, 0.f),
                                fmaxf(dv3 * (a3.y + bfhi(su3)) + b1v.y, 0.f));
        *(float2*)&zs[w4 + 0][2 * cp] = z0;
        *(float2*)&zs[w4 + 1][2 * cp] = z1;
        *(float2*)&zs[w4 + 2][2 * cp] = z2;
        *(float2*)&zs[w4 + 3][2 * cp] = z3;
    }
    float c0 = 0.f, c1 = 0.f, c2 = 0.f, c3 = 0.f;
#pragma unroll 8
    for (int k = 0; k < HID_C; ++k) {
        float wv = W2[k * 64 + lane];
        c0 += zs[w4 + 0][k] * wv;
        c1 += zs[w4 + 1][k] * wv;
        c2 += zs[w4 + 2][k] * wv;
        c3 += zs[w4 + 3][k] * wv;
    }
    g2[(size_t)(d0 + 0) * 64 + lane] = f2bf(dv0 * c0);
    g2[(size_t)(d0 + 1) * 64 + lane] = f2bf(dv1 * c1);
    g2[(size_t)(d0 + 2) * 64 + lane] = f2bf(dv2 * c2);
    g2[(size_t)(d0 + 3) * 64 + lane] = f2bf(dv3 * c3);
}

// ---------------- K3: 4-row fused gather(g2)+bias -> decoder @Wd + bd -> out ----------------
__global__ __launch_bounds__(256) void fused2_kernel(const unsigned short* __restrict__ g2,
                                                     const int* __restrict__ csr,
                                                     const int* __restrict__ rowbeg,
                                                     const int* __restrict__ rowend,
                                                     const float* __restrict__ dinv,
                                                     const float* __restrict__ b2,
                                                     const float* __restrict__ Wd,
                                                     const float* __restrict__ bd,
                                                     float* __restrict__ out) {
    __shared__ float zs[16][64];
    int lane = threadIdx.x & 63;
    int w = threadIdx.x >> 6;
    int cp = lane & 31;
    int d0 = blockIdx.x * 16 + w * 4;
    int S  = __builtin_amdgcn_readfirstlane(rowbeg[d0]);
    int e0 = __builtin_amdgcn_readfirstlane(rowend[d0 + 0]);
    int e1 = __builtin_amdgcn_readfirstlane(rowend[d0 + 1]);
    int e2 = __builtin_amdgcn_readfirstlane(rowend[d0 + 2]);
    int e3 = __builtin_amdgcn_readfirstlane(rowend[d0 + 3]);
    float dv0 = dinv[d0 + 0], dv1 = dinv[d0 + 1], dv2 = dinv[d0 + 2], dv3 = dinv[d0 + 3];
    float2 a0, a1, a2, a3;
    gather4(g2, csr, S, e0, e1, e2, e3, lane, a0, a1, a2, a3);
    const unsigned int* g32 = (const unsigned int*)g2;
    unsigned su0 = g32[(size_t)(d0 + 0) * 32 + cp];
    unsigned su1 = g32[(size_t)(d0 + 1) * 32 + cp];
    unsigned su2 = g32[(size_t)(d0 + 2) * 32 + cp];
    unsigned su3 = g32[(size_t)(d0 + 3) * 32 + cp];
    float2 b2v = *(const float2*)&b2[2 * cp];
    int w4 = w * 4;
    if (lane < 32) {
        float2 z0 = make_float2(dv0 * (a0.x + bflo(su0)) + b2v.x, dv0 * (a0.y + bfhi(su0)) + b2v.y);
        float2 z1 = make_float2(dv1 * (a1.x + bflo(su1)) + b2v.x, dv1 * (a1.y + bfhi(su1)) + b2v.y);
        float2 z2 = make_float2(dv2 * (a2.x + bflo(su2)) + b2v.x, dv2 * (a2.y + bfhi(su2)) + b2v.y);
        float2 z3 = make_float2(dv3 * (a3.x + bflo(su3)) + b2v.x, dv3 * (a3.y + bfhi(su3)) + b2v.y);
        *(float2*)&zs[w4 + 0][2 * cp] = z0;
        *(float2*)&zs[w4 + 1][2 * cp] = z1;
        *(float2*)&zs[w4 + 2][2 * cp] = z2;
        *(float2*)&zs[w4 + 3][2 * cp] = z3;
    }
    float bdl = bd[lane], bdh = bd[64 + lane];
    float c0l = bdl, c0h = bdh, c1l = bdl, c1h = bdh;
    float c2l = bdl, c2h = bdh, c3l = bdl, c3h = bdh;
    for (int k4 = 0; k4 < OUT_C; k4 += 4) {
        float4 z0 = *(const float4*)&zs[w4 + 0][k4];
        float4 z1 = *(const float4*)&zs[w4 + 1][k4];
        float4 z2 = *(const float4*)&zs[w4 + 2][k4];
        float4 z3 = *(const float4*)&zs[w4 + 3][k4];
#pragma unroll
        for (int kk = 0; kk < 4; ++kk) {
            float w0 = Wd[(k4 + kk) * 128 + lane];
            float w1 = Wd[(k4 + kk) * 128 + 64 + lane];
            float zz0 = ((const float*)&z0)[kk];
            float zz1 = ((const float*)&z1)[kk];
            float zz2 = ((const float*)&z2)[kk];
            float zz3 = ((const float*)&z3)[kk];
            c0l += zz0 * w0; c0h += zz0 * w1;
            c1l += zz1 * w0; c1h += zz1 * w1;
            c2l += zz2 * w0; c2h += zz2 * w1;
            c3l += zz3 * w0; c3h += zz3 * w1;
        }
    }
    out[(size_t)(d0 + 0) * 128 + lane] = c0l; out[(size_t)(d0 + 0) * 128 + 64 + lane] = c0h;
    out[(size_t)(d0 + 1) * 128 + lane] = c1l; out[(size_t)(d0 + 1) * 128 + 64 + lane] = c1h;
    out[(size_t)(d0 + 2) * 128 + lane] = c2l; out[(size_t)(d0 + 2) * 128 + 64 + lane] = c2h;
    out[(size_t)(d0 + 3) * 128 + lane] = c3l; out[(size_t)(d0 + 3) * 128 + 64 + lane] = c3h;
}

extern "C" void kernel_launch(void* const* d_in, const int* in_sizes, int n_in,
                              void* d_out, int out_size, void* d_ws, size_t ws_size,
                              hipStream_t stream) {
    const float* x = (const float*)d_in[0];
    const int* ei = (const int*)d_in[1];  // int64 ref -> int32 from harness
    const int* src = ei;
    const int* dst = ei + E_EDGES;
    const float* W1 = (const float*)d_in[2];
    const float* b1 = (const float*)d_in[3];
    const float* W2 = (const float*)d_in[4];
    const float* b2 = (const float*)d_in[5];
    const float* Wd = (const float*)d_in[6];
    const float* bd = (const float*)d_in[7];
    float* out = (float*)d_out;

    // ws layout (4-byte units):
    // bcount[256] | rowbeg[NPAD] | rowend[NPAD] | dinv[NPAD] | csr[NBKT*CSR_CAP] | g2[(N+1)*64 bf16]
    int* bcount = (int*)d_ws;
    int* rowbeg = bcount + 256;
    int* rowend = rowbeg + NPAD;
    float* dinv = (float*)(rowend + NPAD);
    int* csr = (int*)(dinv + NPAD);
    unsigned short* g2 = (unsigned short*)(csr + NBKT * CSR_CAP);
    // aliases into d_out (51.2 MB): g1 at [0, 12.82MB), bbuf at [16MB, 28.9MB)
    unsigned short* g1 = (unsigned short*)out;            // dead before fused2 writes out
    unsigned int* bbuf = (unsigned int*)((char*)d_out + 16000000);  // dead after p2_build

    const int B = 256;
    const int EB = (E_EDGES + 4095) / 4096;  // 391

    // ---- build bucketed CSR + rowbeg/rowend/dinv ----
    p0_zero<<<1, B, 0, stream>>>(bcount, g1, g2);
    p1c_bin<<<EB, B, 0, stream>>>(src, dst, bcount, bbuf, E_EDGES);
    p2_build<<<NBKT, B, 0, stream>>>(bbuf, bcount, csr, rowbeg, rowend, dinv);

    // ---- layer 1 transform (MFMA): g1 = bf16((x @ W1) * dinv) ----
    gemm1_kernel<<<(N_NODES + 63) / 64, B, 0, stream>>>(x, W1, dinv, g1);
    // ---- fused: aggregate(g1) + b1 + relu, @W2, *dinv -> g2 ----
    fused1_kernel<<<N_NODES / 16, B, 0, stream>>>(g1, csr, rowbeg, rowend, dinv, b1, W2, g2);
    // ---- fused: aggregate(g2) + b2, decoder @Wd + bd -> out ----
    fused2_kernel<<<N_NODES / 16, B, 0, stream>>>(g2, csr, rowbeg, rowend, dinv, b2, Wd, bd, out);
}